// Round 6
// baseline (343.321 us; speedup 1.0000x reference)
//
#include <hip/hip_runtime.h>
#include <hip/hip_bf16.h>

typedef short bf16x8 __attribute__((ext_vector_type(8)));
typedef float f32x4 __attribute__((ext_vector_type(4)));

#define TPB 512

__device__ __forceinline__ unsigned short f2bf(float f) {
  unsigned int u = __float_as_uint(f);
  u = (u + 0x7FFFu + ((u >> 16) & 1u)) >> 16;
  return (unsigned short)u;
}

// LDS map (ushort element units) — overlaid lifetimes:
//   [0..8192)     sWin [64][128] swizzled          (staging -> af regs)
//   [0..18432)    Q [4][64][32]swz + K [4][64][40] (phase 1 -> aq/bk regs)  overlays sWin
//   [0..18432)    P [4][64][72]                    (phase 2 -> ap regs)     overlays Q+K exactly
//   [0..8192)     ATT [64][128] swizzled           (PV out -> proj)         overlays P
//   [18432..26624) VT [4][32][64]swz               (phase 1 -> bv regs)
#define Q_OFF   0
#define K_OFF   8192
#define P_OFF   0
#define ATT_OFF 0
#define VT_OFF  18432
#define SMEM_ELEMS 26624 // 53,248 B -> 3 blocks/CU (159,744 <= 163,840)

__global__ void prep_weights(const float* __restrict__ wqkv,
                             const float* __restrict__ wproj,
                             unsigned short* __restrict__ wt) {
  int idx = blockIdx.x * 256 + threadIdx.x;
  if (idx < 384 * 128) {                 // wqkvT[n][k] = bf16(wqkv[k][n])
    int n = idx >> 7, k = idx & 127;
    wt[idx] = f2bf(wqkv[k * 384 + n]);
  } else if (idx < 384 * 128 + 128 * 128) { // wprojT[c][k] = bf16(wproj[k][c])
    int j = idx - 384 * 128;
    int c = j >> 7, k = j & 127;
    wt[idx] = f2bf(wproj[k * 128 + c]);
  }
}

__launch_bounds__(TPB, 6)
__global__ void win_attn(const float* __restrict__ x,
                         const float* __restrict__ bqkv,
                         const float* __restrict__ bproj,
                         const unsigned short* __restrict__ wt,
                         float* __restrict__ out) {
  __shared__ __align__(16) unsigned short smem[SMEM_ELEMS];
  const int tid  = threadIdx.x;
  const int wave = tid >> 6;
  const int lane = tid & 63;
  const int g    = lane >> 4;   // 16-lane group id (0..3)
  const int l15  = lane & 15;

  const int wid = blockIdx.x;
  const int b = wid >> 8, wh = (wid >> 4) & 15, ww = wid & 15;
  const size_t winbase = (((size_t)b * 112 + wh * 7) * 112 + ww * 7) * 128;

  const unsigned short* wqkvT  = wt;               // [384][128] bf16
  const unsigned short* wprojT = wt + 384 * 128;   // [128][128] bf16

  // ---------- stage window (fp32 -> bf16) -> sWin [64][128], XOR-swizzled ----------
  for (int q = tid; q < 2048; q += TPB) {
    int row = q >> 5, c4 = q & 31;
    ushort4 v4 = {0, 0, 0, 0};
    if (row < 49) {
      const float4* src = (const float4*)(x + winbase + ((row / 7) * 112 + (row % 7)) * 128);
      float4 f = src[c4];
      v4.x = f2bf(f.x); v4.y = f2bf(f.y); v4.z = f2bf(f.z); v4.w = f2bf(f.w);
    }
    int dst = row * 128 + ((c4 * 4) ^ ((row & 7) << 3));
    *(ushort4*)(&smem[dst]) = v4;
  }
  __syncthreads();

  // ---------- phase 1: QKV = win @ w_qkv + b_qkv ----------
  bf16x8 af[4][4];
#pragma unroll
  for (int mt = 0; mt < 4; mt++)
#pragma unroll
    for (int kt = 0; kt < 4; kt++) {
      int row = mt * 16 + l15;
      int colE = kt * 32 + g * 8;
      af[mt][kt] = *(const bf16x8*)(&smem[row * 128 + (colE ^ ((row & 7) << 3))]);
    }
  __syncthreads();   // af in regs; Q/K/VT may now be written

  const f32x4 zero4 = {0.f, 0.f, 0.f, 0.f};

#pragma unroll
  for (int i = 0; i < 3; i++) {
    int nt = wave * 3 + i;          // 0..23 (n-tile of 384)
    int n  = nt * 16 + l15;         // output column
    float bias = bqkv[n];

    bf16x8 bw[4];
#pragma unroll
    for (int kt = 0; kt < 4; kt++)
      bw[kt] = *(const bf16x8*)(wqkvT + n * 128 + kt * 32 + g * 8);

    f32x4 acc[4] = {zero4, zero4, zero4, zero4};
#pragma unroll
    for (int kt = 0; kt < 4; kt++)
#pragma unroll
      for (int mt = 0; mt < 4; mt++)
        acc[mt] = __builtin_amdgcn_mfma_f32_16x16x32_bf16(af[mt][kt], bw[kt], acc[mt], 0, 0, 0);

    int sec = n >> 7;        // 0=Q 1=K 2=V
    int hn  = n & 127;
    int h   = hn >> 5;
    int d   = hn & 31;
#pragma unroll
    for (int mt = 0; mt < 4; mt++)
#pragma unroll
      for (int r = 0; r < 4; r++) {
        int tok = mt * 16 + g * 4 + r;          // D row = 4*g + r  (m89-verified)
        unsigned short u = f2bf(acc[mt][r] + bias);
        if (sec == 0)
          smem[Q_OFF + h * 2048 + tok * 32 + ((((d >> 3) + (tok >> 1)) & 3) << 3) + (d & 7)] = u;
        else if (sec == 1)
          smem[K_OFF + h * 2560 + tok * 40 + d] = u;
        else
          smem[VT_OFF + h * 2048 + d * 64 + ((((tok >> 3) + d) & 7) << 3) + (tok & 7)] = u;
      }
  }
  __syncthreads();

  // ---------- phase 2: attention (wave-pair per head) ----------
  const int h    = wave >> 1;
  const int half = wave & 1;        // query rows 0..31 or 32..63
  const float scale = 0.17677669529663687f; // 1/sqrt(32)

  bf16x8 aq[2];
#pragma unroll
  for (int m2 = 0; m2 < 2; m2++) {
    int row = (half * 2 + m2) * 16 + l15;
    int gq = (g + (row >> 1)) & 3;
    aq[m2] = *(const bf16x8*)(&smem[Q_OFF + h * 2048 + row * 32 + gq * 8]);
  }
  bf16x8 bk[4];
#pragma unroll
  for (int nt = 0; nt < 4; nt++) {
    int row = nt * 16 + l15;
    bk[nt] = *(const bf16x8*)(&smem[K_OFF + h * 2560 + row * 40 + g * 8]);
  }
  __syncthreads();   // aq/bk in regs; P may now overlay Q/K

  f32x4 s[2][4];
#pragma unroll
  for (int m2 = 0; m2 < 2; m2++)
#pragma unroll
    for (int nt = 0; nt < 4; nt++)
      s[m2][nt] = __builtin_amdgcn_mfma_f32_16x16x32_bf16(aq[m2], bk[nt], zero4, 0, 0, 0);

  // softmax over cols (49 valid), rows live across 16-lane group g
#pragma unroll
  for (int m2 = 0; m2 < 2; m2++)
#pragma unroll
    for (int r = 0; r < 4; r++) {
      float mx = -1e30f;
#pragma unroll
      for (int nt = 0; nt < 4; nt++) {
        float v = s[m2][nt][r] * scale;
        if (nt * 16 + l15 > 48) v = -1e30f;
        s[m2][nt][r] = v;
        mx = fmaxf(mx, v);
      }
      mx = fmaxf(mx, __shfl_xor(mx, 1));
      mx = fmaxf(mx, __shfl_xor(mx, 2));
      mx = fmaxf(mx, __shfl_xor(mx, 4));
      mx = fmaxf(mx, __shfl_xor(mx, 8));
      float sum = 0.f;
#pragma unroll
      for (int nt = 0; nt < 4; nt++) {
        float p = __expf(s[m2][nt][r] - mx);
        s[m2][nt][r] = p;
        sum += p;
      }
      sum += __shfl_xor(sum, 1);
      sum += __shfl_xor(sum, 2);
      sum += __shfl_xor(sum, 4);
      sum += __shfl_xor(sum, 8);
      float inv = 1.f / sum;
#pragma unroll
      for (int nt = 0; nt < 4; nt++) s[m2][nt][r] *= inv;
    }

  // P -> LDS (bf16), own rows only
#pragma unroll
  for (int m2 = 0; m2 < 2; m2++)
#pragma unroll
    for (int nt = 0; nt < 4; nt++)
#pragma unroll
      for (int r = 0; r < 4; r++) {
        int tokq = (half * 2 + m2) * 16 + g * 4 + r;
        int tokk = nt * 16 + l15;
        smem[P_OFF + h * 4608 + tokq * 72 + tokk] = f2bf(s[m2][nt][r]);
      }
  __syncthreads();

  // PV
  bf16x8 ap[2][2];
#pragma unroll
  for (int m2 = 0; m2 < 2; m2++)
#pragma unroll
    for (int kt = 0; kt < 2; kt++) {
      int row = (half * 2 + m2) * 16 + l15;
      ap[m2][kt] = *(const bf16x8*)(&smem[P_OFF + h * 4608 + row * 72 + kt * 32 + g * 8]);
    }
  bf16x8 bv[2][2];
#pragma unroll
  for (int nt2 = 0; nt2 < 2; nt2++)
#pragma unroll
    for (int kt = 0; kt < 2; kt++) {
      int row = nt2 * 16 + l15;   // d index
      int gv = (kt * 4 + g + row) & 7;
      bv[nt2][kt] = *(const bf16x8*)(&smem[VT_OFF + h * 2048 + row * 64 + gv * 8]);
    }
  __syncthreads();   // ap/bv in regs; ATT may now overlay P

  f32x4 o[2][2] = {{zero4, zero4}, {zero4, zero4}};
#pragma unroll
  for (int kt = 0; kt < 2; kt++)
#pragma unroll
    for (int m2 = 0; m2 < 2; m2++)
#pragma unroll
      for (int nt2 = 0; nt2 < 2; nt2++)
        o[m2][nt2] = __builtin_amdgcn_mfma_f32_16x16x32_bf16(ap[m2][kt], bv[nt2][kt], o[m2][nt2], 0, 0, 0);

#pragma unroll
  for (int m2 = 0; m2 < 2; m2++)
#pragma unroll
    for (int nt2 = 0; nt2 < 2; nt2++)
#pragma unroll
      for (int r = 0; r < 4; r++) {
        int tok = (half * 2 + m2) * 16 + g * 4 + r;
        int col = h * 32 + nt2 * 16 + l15;
        smem[ATT_OFF + tok * 128 + (col ^ ((tok & 7) << 3))] = f2bf(o[m2][nt2][r]);
      }
  __syncthreads();

  // ---------- phase 4: proj + bias + store (fp32 out) ----------
  const int ccol = wave * 16 + l15;
  float biasp = bproj[ccol];
  f32x4 po[4] = {zero4, zero4, zero4, zero4};
#pragma unroll
  for (int kt = 0; kt < 4; kt++) {
    bf16x8 bwp = *(const bf16x8*)(wprojT + ccol * 128 + kt * 32 + g * 8);
#pragma unroll
    for (int mt = 0; mt < 4; mt++) {
      int row = mt * 16 + l15;
      int colE = kt * 32 + g * 8;
      bf16x8 aa = *(const bf16x8*)(&smem[ATT_OFF + row * 128 + (colE ^ ((row & 7) << 3))]);
      po[mt] = __builtin_amdgcn_mfma_f32_16x16x32_bf16(aa, bwp, po[mt], 0, 0, 0);
    }
  }
#pragma unroll
  for (int mt = 0; mt < 4; mt++)
#pragma unroll
    for (int r = 0; r < 4; r++) {
      int tok = mt * 16 + g * 4 + r;
      if (tok < 49) {
        size_t off = winbase + ((size_t)(tok / 7) * 112 + (tok % 7)) * 128 + ccol;
        out[off] = po[mt][r] + biasp;
      }
    }
}

extern "C" void kernel_launch(void* const* d_in, const int* in_sizes, int n_in,
                              void* d_out, int out_size, void* d_ws, size_t ws_size,
                              hipStream_t stream) {
  (void)in_sizes; (void)n_in; (void)out_size; (void)ws_size;
  const float* x     = (const float*)d_in[0];
  const float* wqkv  = (const float*)d_in[1];
  const float* bqkv  = (const float*)d_in[2];
  const float* wproj = (const float*)d_in[3];
  const float* bproj = (const float*)d_in[4];
  unsigned short* wt = (unsigned short*)d_ws;   // 131072 B: wqkvT + wprojT (bf16)

  hipLaunchKernelGGL(prep_weights, dim3(256), dim3(256), 0, stream, wqkv, wproj, wt);
  hipLaunchKernelGGL(win_attn, dim3(4096), dim3(TPB), 0, stream,
                     x, bqkv, bproj, wt, (float*)d_out);
}

// Round 7
// 151.067 us; speedup vs baseline: 2.2726x; 2.2726x over previous
//
#include <hip/hip_runtime.h>
#include <hip/hip_bf16.h>

typedef short bf16x8 __attribute__((ext_vector_type(8)));
typedef float f32x4 __attribute__((ext_vector_type(4)));

#define TPB 512

__device__ __forceinline__ unsigned short f2bf(float f) {
  unsigned int u = __float_as_uint(f);
  u = (u + 0x7FFFu + ((u >> 16) & 1u)) >> 16;
  return (unsigned short)u;
}

// LDS map (ushort element units) — overlaid lifetimes:
//   [0..8192)     sWin [64][128] swizzled          (staging -> af regs)
//   [0..18432)    Q [4][64][32]swz + K [4][64][40] (phase 1 -> aq/bk regs)  overlays sWin
//   [0..18432)    P [4][64][72]                    (phase 2 -> ap regs)     overlays Q+K exactly
//   [0..8192)     ATT [64][128] swizzled           (PV out -> proj)         overlays P
//   [18432..26624) VT [4][32][64]swz               (phase 1 -> bv regs)
#define Q_OFF   0
#define K_OFF   8192
#define P_OFF   0
#define ATT_OFF 0
#define VT_OFF  18432
#define SMEM_ELEMS 26624 // 53,248 B -> 3 blocks/CU (159,744 <= 163,840)

__global__ void prep_weights(const float* __restrict__ wqkv,
                             const float* __restrict__ wproj,
                             unsigned short* __restrict__ wt) {
  int idx = blockIdx.x * 256 + threadIdx.x;
  if (idx < 384 * 128) {                 // wqkvT[n][k] = bf16(wqkv[k][n])
    int n = idx >> 7, k = idx & 127;
    wt[idx] = f2bf(wqkv[k * 384 + n]);
  } else if (idx < 384 * 128 + 128 * 128) { // wprojT[c][k] = bf16(wproj[k][c])
    int j = idx - 384 * 128;
    int c = j >> 7, k = j & 127;
    wt[idx] = f2bf(wproj[k * 128 + c]);
  }
}

__launch_bounds__(TPB, 4)   // r6 lesson: (TPB,6) capped VGPR at 40 -> spills (731 MB scratch writes)
__global__ void win_attn(const float* __restrict__ x,
                         const float* __restrict__ bqkv,
                         const float* __restrict__ bproj,
                         const unsigned short* __restrict__ wt,
                         float* __restrict__ out) {
  __shared__ __align__(16) unsigned short smem[SMEM_ELEMS];
  const int tid  = threadIdx.x;
  const int wave = tid >> 6;
  const int lane = tid & 63;
  const int g    = lane >> 4;   // 16-lane group id (0..3)
  const int l15  = lane & 15;

  const int wid = blockIdx.x;
  const int b = wid >> 8, wh = (wid >> 4) & 15, ww = wid & 15;
  const size_t winbase = (((size_t)b * 112 + wh * 7) * 112 + ww * 7) * 128;

  const unsigned short* wqkvT  = wt;               // [384][128] bf16
  const unsigned short* wprojT = wt + 384 * 128;   // [128][128] bf16

  // ---------- stage window (fp32 -> bf16) -> sWin [64][128], XOR-swizzled ----------
  for (int q = tid; q < 2048; q += TPB) {
    int row = q >> 5, c4 = q & 31;
    ushort4 v4 = {0, 0, 0, 0};
    if (row < 49) {
      const float4* src = (const float4*)(x + winbase + ((row / 7) * 112 + (row % 7)) * 128);
      float4 f = src[c4];
      v4.x = f2bf(f.x); v4.y = f2bf(f.y); v4.z = f2bf(f.z); v4.w = f2bf(f.w);
    }
    int dst = row * 128 + ((c4 * 4) ^ ((row & 7) << 3));
    *(ushort4*)(&smem[dst]) = v4;
  }
  __syncthreads();

  // ---------- phase 1: QKV = win @ w_qkv + b_qkv ----------
  bf16x8 af[4][4];
#pragma unroll
  for (int mt = 0; mt < 4; mt++)
#pragma unroll
    for (int kt = 0; kt < 4; kt++) {
      int row = mt * 16 + l15;
      int colE = kt * 32 + g * 8;
      af[mt][kt] = *(const bf16x8*)(&smem[row * 128 + (colE ^ ((row & 7) << 3))]);
    }
  __syncthreads();   // af in regs; Q/K/VT may now be written

  const f32x4 zero4 = {0.f, 0.f, 0.f, 0.f};

#pragma unroll
  for (int i = 0; i < 3; i++) {
    int nt = wave * 3 + i;          // 0..23 (n-tile of 384)
    int n  = nt * 16 + l15;         // output column
    float bias = bqkv[n];

    bf16x8 bw[4];
#pragma unroll
    for (int kt = 0; kt < 4; kt++)
      bw[kt] = *(const bf16x8*)(wqkvT + n * 128 + kt * 32 + g * 8);

    f32x4 acc[4] = {zero4, zero4, zero4, zero4};
#pragma unroll
    for (int kt = 0; kt < 4; kt++)
#pragma unroll
      for (int mt = 0; mt < 4; mt++)
        acc[mt] = __builtin_amdgcn_mfma_f32_16x16x32_bf16(af[mt][kt], bw[kt], acc[mt], 0, 0, 0);

    int sec = n >> 7;        // 0=Q 1=K 2=V
    int hn  = n & 127;
    int h   = hn >> 5;
    int d   = hn & 31;
#pragma unroll
    for (int mt = 0; mt < 4; mt++)
#pragma unroll
      for (int r = 0; r < 4; r++) {
        int tok = mt * 16 + g * 4 + r;          // D row = 4*g + r  (m89-verified)
        unsigned short u = f2bf(acc[mt][r] + bias);
        if (sec == 0)
          smem[Q_OFF + h * 2048 + tok * 32 + ((((d >> 3) + (tok >> 1)) & 3) << 3) + (d & 7)] = u;
        else if (sec == 1)
          smem[K_OFF + h * 2560 + tok * 40 + d] = u;
        else
          smem[VT_OFF + h * 2048 + d * 64 + ((((tok >> 3) + d) & 7) << 3) + (tok & 7)] = u;
      }
  }
  __syncthreads();

  // ---------- phase 2: attention (wave-pair per head) ----------
  const int h    = wave >> 1;
  const int half = wave & 1;        // query rows 0..31 or 32..63
  const float scale = 0.17677669529663687f; // 1/sqrt(32)

  bf16x8 aq[2];
#pragma unroll
  for (int m2 = 0; m2 < 2; m2++) {
    int row = (half * 2 + m2) * 16 + l15;
    int gq = (g + (row >> 1)) & 3;
    aq[m2] = *(const bf16x8*)(&smem[Q_OFF + h * 2048 + row * 32 + gq * 8]);
  }
  bf16x8 bk[4];
#pragma unroll
  for (int nt = 0; nt < 4; nt++) {
    int row = nt * 16 + l15;
    bk[nt] = *(const bf16x8*)(&smem[K_OFF + h * 2560 + row * 40 + g * 8]);
  }
  __syncthreads();   // aq/bk in regs; P may now overlay Q/K

  f32x4 s[2][4];
#pragma unroll
  for (int m2 = 0; m2 < 2; m2++)
#pragma unroll
    for (int nt = 0; nt < 4; nt++)
      s[m2][nt] = __builtin_amdgcn_mfma_f32_16x16x32_bf16(aq[m2], bk[nt], zero4, 0, 0, 0);

  // softmax over cols (49 valid), rows live across 16-lane group g
#pragma unroll
  for (int m2 = 0; m2 < 2; m2++)
#pragma unroll
    for (int r = 0; r < 4; r++) {
      float mx = -1e30f;
#pragma unroll
      for (int nt = 0; nt < 4; nt++) {
        float v = s[m2][nt][r] * scale;
        if (nt * 16 + l15 > 48) v = -1e30f;
        s[m2][nt][r] = v;
        mx = fmaxf(mx, v);
      }
      mx = fmaxf(mx, __shfl_xor(mx, 1));
      mx = fmaxf(mx, __shfl_xor(mx, 2));
      mx = fmaxf(mx, __shfl_xor(mx, 4));
      mx = fmaxf(mx, __shfl_xor(mx, 8));
      float sum = 0.f;
#pragma unroll
      for (int nt = 0; nt < 4; nt++) {
        float p = __expf(s[m2][nt][r] - mx);
        s[m2][nt][r] = p;
        sum += p;
      }
      sum += __shfl_xor(sum, 1);
      sum += __shfl_xor(sum, 2);
      sum += __shfl_xor(sum, 4);
      sum += __shfl_xor(sum, 8);
      float inv = 1.f / sum;
#pragma unroll
      for (int nt = 0; nt < 4; nt++) s[m2][nt][r] *= inv;
    }

  // P -> LDS (bf16), own rows only
#pragma unroll
  for (int m2 = 0; m2 < 2; m2++)
#pragma unroll
    for (int nt = 0; nt < 4; nt++)
#pragma unroll
      for (int r = 0; r < 4; r++) {
        int tokq = (half * 2 + m2) * 16 + g * 4 + r;
        int tokk = nt * 16 + l15;
        smem[P_OFF + h * 4608 + tokq * 72 + tokk] = f2bf(s[m2][nt][r]);
      }
  __syncthreads();

  // PV
  bf16x8 ap[2][2];
#pragma unroll
  for (int m2 = 0; m2 < 2; m2++)
#pragma unroll
    for (int kt = 0; kt < 2; kt++) {
      int row = (half * 2 + m2) * 16 + l15;
      ap[m2][kt] = *(const bf16x8*)(&smem[P_OFF + h * 4608 + row * 72 + kt * 32 + g * 8]);
    }
  bf16x8 bv[2][2];
#pragma unroll
  for (int nt2 = 0; nt2 < 2; nt2++)
#pragma unroll
    for (int kt = 0; kt < 2; kt++) {
      int row = nt2 * 16 + l15;   // d index
      int gv = (kt * 4 + g + row) & 7;
      bv[nt2][kt] = *(const bf16x8*)(&smem[VT_OFF + h * 2048 + row * 64 + gv * 8]);
    }
  __syncthreads();   // ap/bv in regs; ATT may now overlay P

  f32x4 o[2][2] = {{zero4, zero4}, {zero4, zero4}};
#pragma unroll
  for (int kt = 0; kt < 2; kt++)
#pragma unroll
    for (int m2 = 0; m2 < 2; m2++)
#pragma unroll
      for (int nt2 = 0; nt2 < 2; nt2++)
        o[m2][nt2] = __builtin_amdgcn_mfma_f32_16x16x32_bf16(ap[m2][kt], bv[nt2][kt], o[m2][nt2], 0, 0, 0);

#pragma unroll
  for (int m2 = 0; m2 < 2; m2++)
#pragma unroll
    for (int nt2 = 0; nt2 < 2; nt2++)
#pragma unroll
      for (int r = 0; r < 4; r++) {
        int tok = (half * 2 + m2) * 16 + g * 4 + r;
        int col = h * 32 + nt2 * 16 + l15;
        smem[ATT_OFF + tok * 128 + (col ^ ((tok & 7) << 3))] = f2bf(o[m2][nt2][r]);
      }
  __syncthreads();

  // ---------- phase 4: proj + bias + store (fp32 out) ----------
  const int ccol = wave * 16 + l15;
  float biasp = bproj[ccol];
  f32x4 po[4] = {zero4, zero4, zero4, zero4};
#pragma unroll
  for (int kt = 0; kt < 4; kt++) {
    bf16x8 bwp = *(const bf16x8*)(wprojT + ccol * 128 + kt * 32 + g * 8);
#pragma unroll
    for (int mt = 0; mt < 4; mt++) {
      int row = mt * 16 + l15;
      int colE = kt * 32 + g * 8;
      bf16x8 aa = *(const bf16x8*)(&smem[ATT_OFF + row * 128 + (colE ^ ((row & 7) << 3))]);
      po[mt] = __builtin_amdgcn_mfma_f32_16x16x32_bf16(aa, bwp, po[mt], 0, 0, 0);
    }
  }
#pragma unroll
  for (int mt = 0; mt < 4; mt++)
#pragma unroll
    for (int r = 0; r < 4; r++) {
      int tok = mt * 16 + g * 4 + r;
      if (tok < 49) {
        size_t off = winbase + ((size_t)(tok / 7) * 112 + (tok % 7)) * 128 + ccol;
        out[off] = po[mt][r] + biasp;
      }
    }
}

extern "C" void kernel_launch(void* const* d_in, const int* in_sizes, int n_in,
                              void* d_out, int out_size, void* d_ws, size_t ws_size,
                              hipStream_t stream) {
  (void)in_sizes; (void)n_in; (void)out_size; (void)ws_size;
  const float* x     = (const float*)d_in[0];
  const float* wqkv  = (const float*)d_in[1];
  const float* bqkv  = (const float*)d_in[2];
  const float* wproj = (const float*)d_in[3];
  const float* bproj = (const float*)d_in[4];
  unsigned short* wt = (unsigned short*)d_ws;   // 131072 B: wqkvT + wprojT (bf16)

  hipLaunchKernelGGL(prep_weights, dim3(256), dim3(256), 0, stream, wqkv, wproj, wt);
  hipLaunchKernelGGL(win_attn, dim3(4096), dim3(TPB), 0, stream,
                     x, bqkv, bproj, wt, (float*)d_out);
}

// Round 8
// 124.649 us; speedup vs baseline: 2.7543x; 1.2119x over previous
//
#include <hip/hip_runtime.h>
#include <hip/hip_bf16.h>

typedef short bf16x8 __attribute__((ext_vector_type(8)));
typedef float f32x4 __attribute__((ext_vector_type(4)));

#define TPB 512

// HW bf16 convert (RNE) — compiler emits v_cvt_pk_bf16_f32; do NOT hand-roll (r7: manual
// integer-RNE was ~4 VALU/value and the extra temporaries caused spills under the VGPR cap).
__device__ __forceinline__ unsigned short f2bf(float f) {
  __hip_bfloat16 h = __float2bfloat16(f);
  return __builtin_bit_cast(unsigned short, h);
}

// LDS map (ushort element units) — overlaid lifetimes (usable LDS/CU = 128 KiB, r3-r7 fit):
//   [0..8192)      sWin [64][128] swizzled          (staging -> af regs)
//   [0..20480)     Q [4][64][40] + K [4][64][40]    (phase 1 -> aq/bk regs)  overlays sWin
//   [0..18432)     P [4][64][72]                    (phase 2 -> ap regs)     overlays Q/K
//   [0..8192)      ATT [64][128] swizzled           (PV out -> proj)         overlays P
//   [20480..29696) VT [4][32][72]                   (phase 1 -> bv regs)
#define Q_OFF   0
#define K_OFF   10240
#define P_OFF   0
#define ATT_OFF 0
#define VT_OFF  20480
#define SMEM_ELEMS 29696 // 59,392 B -> 2 blocks/CU (118,784 <= 131,072)

__global__ void prep_weights(const float* __restrict__ wqkv,
                             const float* __restrict__ wproj,
                             unsigned short* __restrict__ wt) {
  int idx = blockIdx.x * 256 + threadIdx.x;
  if (idx < 384 * 128) {                 // wqkvT[n][k] = bf16(wqkv[k][n])
    int n = idx >> 7, k = idx & 127;
    wt[idx] = f2bf(wqkv[k * 384 + n]);
  } else if (idx < 384 * 128 + 128 * 128) { // wprojT[c][k] = bf16(wproj[k][c])
    int j = idx - 384 * 128;
    int c = j >> 7, k = j & 127;
    wt[idx] = f2bf(wproj[k * 128 + c]);
  }
}

__launch_bounds__(TPB, 4)   // r6: (TPB,6) caps VGPR at 40 -> spills. r5: (TPB,4) -> 64, clean.
__global__ void win_attn(const float* __restrict__ x,
                         const float* __restrict__ bqkv,
                         const float* __restrict__ bproj,
                         const unsigned short* __restrict__ wt,
                         float* __restrict__ out) {
  __shared__ __align__(16) unsigned short smem[SMEM_ELEMS];
  const int tid  = threadIdx.x;
  const int wave = tid >> 6;
  const int lane = tid & 63;
  const int g    = lane >> 4;   // 16-lane group id (0..3)
  const int l15  = lane & 15;

  const int wid = blockIdx.x;
  const int b = wid >> 8, wh = (wid >> 4) & 15, ww = wid & 15;
  const size_t winbase = (((size_t)b * 112 + wh * 7) * 112 + ww * 7) * 128;

  const unsigned short* wqkvT  = wt;               // [384][128] bf16
  const unsigned short* wprojT = wt + 384 * 128;   // [128][128] bf16

  // ---------- stage window (fp32 -> bf16) -> sWin [64][128], XOR-swizzled ----------
  for (int q = tid; q < 2048; q += TPB) {
    int row = q >> 5, c4 = q & 31;
    ushort4 v4 = {0, 0, 0, 0};
    if (row < 49) {
      const float4* src = (const float4*)(x + winbase + ((row / 7) * 112 + (row % 7)) * 128);
      float4 f = src[c4];
      v4.x = f2bf(f.x); v4.y = f2bf(f.y); v4.z = f2bf(f.z); v4.w = f2bf(f.w);
    }
    int dst = row * 128 + ((c4 * 4) ^ ((row & 7) << 3));
    *(ushort4*)(&smem[dst]) = v4;
  }
  __syncthreads();

  // ---------- phase 1: QKV = win @ w_qkv + b_qkv ----------
  bf16x8 af[4][4];
#pragma unroll
  for (int mt = 0; mt < 4; mt++)
#pragma unroll
    for (int kt = 0; kt < 4; kt++) {
      int row = mt * 16 + l15;
      int colE = kt * 32 + g * 8;
      af[mt][kt] = *(const bf16x8*)(&smem[row * 128 + (colE ^ ((row & 7) << 3))]);
    }
  __syncthreads();   // af in regs; Q/K/VT may now be written

  const f32x4 zero4 = {0.f, 0.f, 0.f, 0.f};

#pragma unroll
  for (int i = 0; i < 3; i++) {
    int nt = wave * 3 + i;          // 0..23 (n-tile of 384)
    int n  = nt * 16 + l15;         // output column
    float bias = bqkv[n];

    bf16x8 bw[4];
#pragma unroll
    for (int kt = 0; kt < 4; kt++)
      bw[kt] = *(const bf16x8*)(wqkvT + n * 128 + kt * 32 + g * 8);

    f32x4 acc[4] = {zero4, zero4, zero4, zero4};
#pragma unroll
    for (int kt = 0; kt < 4; kt++)
#pragma unroll
      for (int mt = 0; mt < 4; mt++)
        acc[mt] = __builtin_amdgcn_mfma_f32_16x16x32_bf16(af[mt][kt], bw[kt], acc[mt], 0, 0, 0);

    int sec = nt >> 3;       // 0=Q 1=K 2=V  (uniform per (wave,i))
    int hn  = n & 127;
    int h   = hn >> 5;
    int d   = hn & 31;
    if (sec == 2) {
      // V^T: 4 consecutive toks per mt -> packed ds_write_b64
#pragma unroll
      for (int mt = 0; mt < 4; mt++) {
        int tok0 = mt * 16 + g * 4;
        ushort4 pv;
        pv.x = f2bf(acc[mt][0] + bias);
        pv.y = f2bf(acc[mt][1] + bias);
        pv.z = f2bf(acc[mt][2] + bias);
        pv.w = f2bf(acc[mt][3] + bias);
        *(ushort4*)(&smem[VT_OFF + h * 2304 + d * 72 + tok0]) = pv;
      }
    } else {
      const int base = (sec == 0 ? Q_OFF : K_OFF) + h * 2560 + d;
#pragma unroll
      for (int mt = 0; mt < 4; mt++)
#pragma unroll
        for (int r = 0; r < 4; r++) {
          int tok = mt * 16 + g * 4 + r;        // D row = 4*g + r  (m89-verified)
          smem[base + tok * 40] = f2bf(acc[mt][r] + bias);
        }
    }
  }
  __syncthreads();

  // ---------- phase 2: attention (wave-pair per head) ----------
  const int h    = wave >> 1;
  const int half = wave & 1;        // query rows 0..31 or 32..63
  const float scale = 0.17677669529663687f; // 1/sqrt(32)

  bf16x8 aq[2];
#pragma unroll
  for (int m2 = 0; m2 < 2; m2++) {
    int row = (half * 2 + m2) * 16 + l15;
    aq[m2] = *(const bf16x8*)(&smem[Q_OFF + h * 2560 + row * 40 + g * 8]);
  }
  bf16x8 bk[4];
#pragma unroll
  for (int nt = 0; nt < 4; nt++) {
    int row = nt * 16 + l15;
    bk[nt] = *(const bf16x8*)(&smem[K_OFF + h * 2560 + row * 40 + g * 8]);
  }
  __syncthreads();   // aq/bk in regs; P may now overlay Q/K

  f32x4 s[2][4];
#pragma unroll
  for (int m2 = 0; m2 < 2; m2++)
#pragma unroll
    for (int nt = 0; nt < 4; nt++)
      s[m2][nt] = __builtin_amdgcn_mfma_f32_16x16x32_bf16(aq[m2], bk[nt], zero4, 0, 0, 0);

  // softmax over cols (49 valid), rows live across 16-lane group g
#pragma unroll
  for (int m2 = 0; m2 < 2; m2++)
#pragma unroll
    for (int r = 0; r < 4; r++) {
      float mx = -1e30f;
#pragma unroll
      for (int nt = 0; nt < 4; nt++) {
        float v = s[m2][nt][r] * scale;
        if (nt * 16 + l15 > 48) v = -1e30f;
        s[m2][nt][r] = v;
        mx = fmaxf(mx, v);
      }
      mx = fmaxf(mx, __shfl_xor(mx, 1));
      mx = fmaxf(mx, __shfl_xor(mx, 2));
      mx = fmaxf(mx, __shfl_xor(mx, 4));
      mx = fmaxf(mx, __shfl_xor(mx, 8));
      float sum = 0.f;
#pragma unroll
      for (int nt = 0; nt < 4; nt++) {
        float p = __expf(s[m2][nt][r] - mx);
        s[m2][nt][r] = p;
        sum += p;
      }
      sum += __shfl_xor(sum, 1);
      sum += __shfl_xor(sum, 2);
      sum += __shfl_xor(sum, 4);
      sum += __shfl_xor(sum, 8);
      float inv = 1.f / sum;
#pragma unroll
      for (int nt = 0; nt < 4; nt++) s[m2][nt][r] *= inv;
    }

  // P -> LDS (bf16), own rows only
#pragma unroll
  for (int m2 = 0; m2 < 2; m2++)
#pragma unroll
    for (int nt = 0; nt < 4; nt++)
#pragma unroll
      for (int r = 0; r < 4; r++) {
        int tokq = (half * 2 + m2) * 16 + g * 4 + r;
        int tokk = nt * 16 + l15;
        smem[P_OFF + h * 4608 + tokq * 72 + tokk] = f2bf(s[m2][nt][r]);
      }
  __syncthreads();

  // PV
  bf16x8 ap[2][2];
#pragma unroll
  for (int m2 = 0; m2 < 2; m2++)
#pragma unroll
    for (int kt = 0; kt < 2; kt++) {
      int row = (half * 2 + m2) * 16 + l15;
      ap[m2][kt] = *(const bf16x8*)(&smem[P_OFF + h * 4608 + row * 72 + kt * 32 + g * 8]);
    }
  bf16x8 bv[2][2];
#pragma unroll
  for (int nt2 = 0; nt2 < 2; nt2++)
#pragma unroll
    for (int kt = 0; kt < 2; kt++) {
      int row = nt2 * 16 + l15;   // d index
      bv[nt2][kt] = *(const bf16x8*)(&smem[VT_OFF + h * 2304 + row * 72 + kt * 32 + g * 8]);
    }
  __syncthreads();   // ap/bv in regs; ATT may now overlay P

  f32x4 o[2][2] = {{zero4, zero4}, {zero4, zero4}};
#pragma unroll
  for (int kt = 0; kt < 2; kt++)
#pragma unroll
    for (int m2 = 0; m2 < 2; m2++)
#pragma unroll
      for (int nt2 = 0; nt2 < 2; nt2++)
        o[m2][nt2] = __builtin_amdgcn_mfma_f32_16x16x32_bf16(ap[m2][kt], bv[nt2][kt], o[m2][nt2], 0, 0, 0);

#pragma unroll
  for (int m2 = 0; m2 < 2; m2++)
#pragma unroll
    for (int nt2 = 0; nt2 < 2; nt2++)
#pragma unroll
      for (int r = 0; r < 4; r++) {
        int tok = (half * 2 + m2) * 16 + g * 4 + r;
        int col = h * 32 + nt2 * 16 + l15;
        smem[ATT_OFF + tok * 128 + (col ^ ((tok & 7) << 3))] = f2bf(o[m2][nt2][r]);
      }
  __syncthreads();

  // ---------- phase 4: proj + bias + store (fp32 out) ----------
  const int ccol = wave * 16 + l15;
  float biasp = bproj[ccol];
  f32x4 po[4] = {zero4, zero4, zero4, zero4};
#pragma unroll
  for (int kt = 0; kt < 4; kt++) {
    bf16x8 bwp = *(const bf16x8*)(wprojT + ccol * 128 + kt * 32 + g * 8);
#pragma unroll
    for (int mt = 0; mt < 4; mt++) {
      int row = mt * 16 + l15;
      int colE = kt * 32 + g * 8;
      bf16x8 aa = *(const bf16x8*)(&smem[ATT_OFF + row * 128 + (colE ^ ((row & 7) << 3))]);
      po[mt] = __builtin_amdgcn_mfma_f32_16x16x32_bf16(aa, bwp, po[mt], 0, 0, 0);
    }
  }
#pragma unroll
  for (int mt = 0; mt < 4; mt++)
#pragma unroll
    for (int r = 0; r < 4; r++) {
      int tok = mt * 16 + g * 4 + r;
      if (tok < 49) {
        size_t off = winbase + ((size_t)(tok / 7) * 112 + (tok % 7)) * 128 + ccol;
        out[off] = po[mt][r] + biasp;
      }
    }
}

extern "C" void kernel_launch(void* const* d_in, const int* in_sizes, int n_in,
                              void* d_out, int out_size, void* d_ws, size_t ws_size,
                              hipStream_t stream) {
  (void)in_sizes; (void)n_in; (void)out_size; (void)ws_size;
  const float* x     = (const float*)d_in[0];
  const float* wqkv  = (const float*)d_in[1];
  const float* bqkv  = (const float*)d_in[2];
  const float* wproj = (const float*)d_in[3];
  const float* bproj = (const float*)d_in[4];
  unsigned short* wt = (unsigned short*)d_ws;   // 131072 B: wqkvT + wprojT (bf16)

  hipLaunchKernelGGL(prep_weights, dim3(256), dim3(256), 0, stream, wqkv, wproj, wt);
  hipLaunchKernelGGL(win_attn, dim3(4096), dim3(TPB), 0, stream,
                     x, bqkv, bproj, wt, (float*)d_out);
}

// Round 9
// 110.620 us; speedup vs baseline: 3.1036x; 1.1268x over previous
//
#include <hip/hip_runtime.h>
#include <hip/hip_bf16.h>

typedef short bf16x8 __attribute__((ext_vector_type(8)));
typedef float f32x4 __attribute__((ext_vector_type(4)));

#define TPB 512

// HW bf16 convert (RNE) — compiler emits v_cvt_pk_bf16_f32; do NOT hand-roll (r7/r8 lesson).
__device__ __forceinline__ unsigned short f2bf(float f) {
  __hip_bfloat16 h = __float2bfloat16(f);
  return __builtin_bit_cast(unsigned short, h);
}

// LDS map (ushort element units) — overlaid lifetimes (usable LDS/CU = 128 KiB, r3-r7 fit):
//   [0..8192)      sWin [64][128] swizzled          (staging -> af regs)
//   [0..20480)     Q [4][64][40] + K [4][64][40]    (phase 1 -> ak/bq regs)  overlays sWin
//   [0..18432)     P [4][64][72]                    (phase 2 -> ap regs)     overlays Q/K
//   [0..8192)      ATT [64][128] swizzled           (PV out -> proj)         overlays P
//   [20480..29696) VT [4][32][72]                   (phase 1 -> bv regs)
#define Q_OFF   0
#define K_OFF   10240
#define P_OFF   0
#define ATT_OFF 0
#define VT_OFF  20480
#define SMEM_ELEMS 29696 // 59,392 B -> 2 blocks/CU (118,784 <= 131,072)

__global__ void prep_weights(const float* __restrict__ wqkv,
                             const float* __restrict__ wproj,
                             unsigned short* __restrict__ wt) {
  int idx = blockIdx.x * 256 + threadIdx.x;
  if (idx < 384 * 128) {                 // wqkvT[n][k] = bf16(wqkv[k][n])
    int n = idx >> 7, k = idx & 127;
    wt[idx] = f2bf(wqkv[k * 384 + n]);
  } else if (idx < 384 * 128 + 128 * 128) { // wprojT[c][k] = bf16(wproj[k][c])
    int j = idx - 384 * 128;
    int c = j >> 7, k = j & 127;
    wt[idx] = f2bf(wproj[k * 128 + c]);
  }
}

__launch_bounds__(TPB, 4)   // r6: (TPB,6) caps VGPR at 40 -> spills. (TPB,4) is clean.
__global__ void win_attn(const float* __restrict__ x,
                         const float* __restrict__ bqkv,
                         const float* __restrict__ bproj,
                         const unsigned short* __restrict__ wt,
                         float* __restrict__ out) {
  __shared__ __align__(16) unsigned short smem[SMEM_ELEMS];
  const int tid  = threadIdx.x;
  const int wave = tid >> 6;
  const int lane = tid & 63;
  const int g    = lane >> 4;   // 16-lane group id (0..3)
  const int l15  = lane & 15;

  const int wid = blockIdx.x;
  const int b = wid >> 8, wh = (wid >> 4) & 15, ww = wid & 15;
  const size_t winbase = (((size_t)b * 112 + wh * 7) * 112 + ww * 7) * 128;

  const unsigned short* wqkvT  = wt;               // [384][128] bf16
  const unsigned short* wprojT = wt + 384 * 128;   // [128][128] bf16

  const float scale = 0.17677669529663687f; // 1/sqrt(32)

  // ---------- stage window (fp32 -> bf16) -> sWin [64][128], XOR-swizzled ----------
  for (int q = tid; q < 2048; q += TPB) {
    int row = q >> 5, c4 = q & 31;
    ushort4 v4 = {0, 0, 0, 0};
    if (row < 49) {
      const float4* src = (const float4*)(x + winbase + ((row / 7) * 112 + (row % 7)) * 128);
      float4 f = src[c4];
      v4.x = f2bf(f.x); v4.y = f2bf(f.y); v4.z = f2bf(f.z); v4.w = f2bf(f.w);
    }
    int dst = row * 128 + ((c4 * 4) ^ ((row & 7) << 3));
    *(ushort4*)(&smem[dst]) = v4;
  }
  __syncthreads();

  // ---------- phase 1: QKV = win @ w_qkv + b_qkv ----------
  bf16x8 af[4][4];
#pragma unroll
  for (int mt = 0; mt < 4; mt++)
#pragma unroll
    for (int kt = 0; kt < 4; kt++) {
      int row = mt * 16 + l15;
      int colE = kt * 32 + g * 8;
      af[mt][kt] = *(const bf16x8*)(&smem[row * 128 + (colE ^ ((row & 7) << 3))]);
    }
  __syncthreads();   // af in regs; Q/K/VT may now be written

  const f32x4 zero4 = {0.f, 0.f, 0.f, 0.f};

#pragma unroll
  for (int i = 0; i < 3; i++) {
    int nt = wave * 3 + i;          // 0..23 (n-tile of 384)
    int n  = nt * 16 + l15;         // output column
    float bias = bqkv[n];

    bf16x8 bw[4];
#pragma unroll
    for (int kt = 0; kt < 4; kt++)
      bw[kt] = *(const bf16x8*)(wqkvT + n * 128 + kt * 32 + g * 8);

    f32x4 acc[4] = {zero4, zero4, zero4, zero4};
#pragma unroll
    for (int kt = 0; kt < 4; kt++)
#pragma unroll
      for (int mt = 0; mt < 4; mt++)
        acc[mt] = __builtin_amdgcn_mfma_f32_16x16x32_bf16(af[mt][kt], bw[kt], acc[mt], 0, 0, 0);

    int sec = nt >> 3;       // 0=Q 1=K 2=V  (uniform per (wave,i))
    int hn  = n & 127;
    int h   = hn >> 5;
    int d   = hn & 31;
    if (sec == 2) {
      // V^T: 4 consecutive toks per mt -> packed ds_write_b64
#pragma unroll
      for (int mt = 0; mt < 4; mt++) {
        int tok0 = mt * 16 + g * 4;
        ushort4 pv;
        pv.x = f2bf(acc[mt][0] + bias);
        pv.y = f2bf(acc[mt][1] + bias);
        pv.z = f2bf(acc[mt][2] + bias);
        pv.w = f2bf(acc[mt][3] + bias);
        *(ushort4*)(&smem[VT_OFF + h * 2304 + d * 72 + tok0]) = pv;
      }
    } else {
      // Q gets the softmax 1/sqrt(d) scale folded into its store (saves VALU in phase 2)
      const int base = (sec == 0 ? Q_OFF : K_OFF) + h * 2560 + d;
      const float mul = (sec == 0) ? scale : 1.0f;
#pragma unroll
      for (int mt = 0; mt < 4; mt++)
#pragma unroll
        for (int r = 0; r < 4; r++) {
          int tok = mt * 16 + g * 4 + r;        // D row = 4*g + r  (m89-verified)
          smem[base + tok * 40] = f2bf((acc[mt][r] + bias) * mul);
        }
    }
  }
  __syncthreads();

  // ---------- phase 2: attention, swapped QK^T (wave-pair per head) ----------
  // s = mfma(K, Q): D col = q-token (l15), row-regs = k-token (kt*16 + 4g + r).
  // Each l15 lane-quad (g=0..3) holds a full 64-k row of one q -> 2-shuffle softmax.
  const int h    = wave >> 1;
  const int half = wave & 1;        // query rows 0..31 or 32..63

  bf16x8 ak[4];
#pragma unroll
  for (int kt = 0; kt < 4; kt++) {
    int row = kt * 16 + l15;
    ak[kt] = *(const bf16x8*)(&smem[K_OFF + h * 2560 + row * 40 + g * 8]);
  }
  bf16x8 bq[2];
#pragma unroll
  for (int qt = 0; qt < 2; qt++) {
    int row = half * 32 + qt * 16 + l15;
    bq[qt] = *(const bf16x8*)(&smem[Q_OFF + h * 2560 + row * 40 + g * 8]);
  }
  __syncthreads();   // ak/bq in regs; P may now overlay Q/K

  f32x4 s[4][2];
#pragma unroll
  for (int kt = 0; kt < 4; kt++)
#pragma unroll
    for (int qt = 0; qt < 2; qt++)
      s[kt][qt] = __builtin_amdgcn_mfma_f32_16x16x32_bf16(ak[kt], bq[qt], zero4, 0, 0, 0);

#pragma unroll
  for (int qt = 0; qt < 2; qt++) {
    float mx = -1e30f;
#pragma unroll
    for (int kt = 0; kt < 4; kt++)
#pragma unroll
      for (int r = 0; r < 4; r++) {
        float v = s[kt][qt][r];
        if (kt * 16 + g * 4 + r > 48) v = -1e30f;
        s[kt][qt][r] = v;
        mx = fmaxf(mx, v);
      }
    mx = fmaxf(mx, __shfl_xor(mx, 16));
    mx = fmaxf(mx, __shfl_xor(mx, 32));
    float sum = 0.f;
#pragma unroll
    for (int kt = 0; kt < 4; kt++)
#pragma unroll
      for (int r = 0; r < 4; r++) {
        float p = __expf(s[kt][qt][r] - mx);
        s[kt][qt][r] = p;
        sum += p;
      }
    sum += __shfl_xor(sum, 16);
    sum += __shfl_xor(sum, 32);
    float inv = 1.f / sum;
    int q = half * 32 + qt * 16 + l15;
    // P[q][k]: 4 consecutive k per reg-quad -> packed ds_write_b64
#pragma unroll
    for (int kt = 0; kt < 4; kt++) {
      ushort4 pp;
      pp.x = f2bf(s[kt][qt][0] * inv);
      pp.y = f2bf(s[kt][qt][1] * inv);
      pp.z = f2bf(s[kt][qt][2] * inv);
      pp.w = f2bf(s[kt][qt][3] * inv);
      *(ushort4*)(&smem[P_OFF + h * 4608 + q * 72 + kt * 16 + g * 4]) = pp;
    }
  }
  __syncthreads();

  // PV
  bf16x8 ap[2][2];
#pragma unroll
  for (int m2 = 0; m2 < 2; m2++)
#pragma unroll
    for (int kt = 0; kt < 2; kt++) {
      int row = (half * 2 + m2) * 16 + l15;
      ap[m2][kt] = *(const bf16x8*)(&smem[P_OFF + h * 4608 + row * 72 + kt * 32 + g * 8]);
    }
  bf16x8 bv[2][2];
#pragma unroll
  for (int nt2 = 0; nt2 < 2; nt2++)
#pragma unroll
    for (int kt = 0; kt < 2; kt++) {
      int row = nt2 * 16 + l15;   // d index
      bv[nt2][kt] = *(const bf16x8*)(&smem[VT_OFF + h * 2304 + row * 72 + kt * 32 + g * 8]);
    }
  __syncthreads();   // ap/bv in regs; ATT may now overlay P

  f32x4 o[2][2] = {{zero4, zero4}, {zero4, zero4}};
#pragma unroll
  for (int kt = 0; kt < 2; kt++)
#pragma unroll
    for (int m2 = 0; m2 < 2; m2++)
#pragma unroll
      for (int nt2 = 0; nt2 < 2; nt2++)
        o[m2][nt2] = __builtin_amdgcn_mfma_f32_16x16x32_bf16(ap[m2][kt], bv[nt2][kt], o[m2][nt2], 0, 0, 0);

#pragma unroll
  for (int m2 = 0; m2 < 2; m2++)
#pragma unroll
    for (int nt2 = 0; nt2 < 2; nt2++)
#pragma unroll
      for (int r = 0; r < 4; r++) {
        int tok = (half * 2 + m2) * 16 + g * 4 + r;
        int col = h * 32 + nt2 * 16 + l15;
        smem[ATT_OFF + tok * 128 + (col ^ ((tok & 7) << 3))] = f2bf(o[m2][nt2][r]);
      }
  __syncthreads();

  // ---------- phase 4: proj + bias + store (fp32 out) ----------
  const int ccol = wave * 16 + l15;
  float biasp = bproj[ccol];
  f32x4 po[4] = {zero4, zero4, zero4, zero4};
#pragma unroll
  for (int kt = 0; kt < 4; kt++) {
    bf16x8 bwp = *(const bf16x8*)(wprojT + ccol * 128 + kt * 32 + g * 8);
#pragma unroll
    for (int mt = 0; mt < 4; mt++) {
      int row = mt * 16 + l15;
      int colE = kt * 32 + g * 8;
      bf16x8 aa = *(const bf16x8*)(&smem[ATT_OFF + row * 128 + (colE ^ ((row & 7) << 3))]);
      po[mt] = __builtin_amdgcn_mfma_f32_16x16x32_bf16(aa, bwp, po[mt], 0, 0, 0);
    }
  }
#pragma unroll
  for (int mt = 0; mt < 4; mt++)
#pragma unroll
    for (int r = 0; r < 4; r++) {
      int tok = mt * 16 + g * 4 + r;
      if (tok < 49) {
        size_t off = winbase + ((size_t)(tok / 7) * 112 + (tok % 7)) * 128 + ccol;
        out[off] = po[mt][r] + biasp;
      }
    }
}

extern "C" void kernel_launch(void* const* d_in, const int* in_sizes, int n_in,
                              void* d_out, int out_size, void* d_ws, size_t ws_size,
                              hipStream_t stream) {
  (void)in_sizes; (void)n_in; (void)out_size; (void)ws_size;
  const float* x     = (const float*)d_in[0];
  const float* wqkv  = (const float*)d_in[1];
  const float* bqkv  = (const float*)d_in[2];
  const float* wproj = (const float*)d_in[3];
  const float* bproj = (const float*)d_in[4];
  unsigned short* wt = (unsigned short*)d_ws;   // 131072 B: wqkvT + wprojT (bf16)

  hipLaunchKernelGGL(prep_weights, dim3(256), dim3(256), 0, stream, wqkv, wproj, wt);
  hipLaunchKernelGGL(win_attn, dim3(4096), dim3(TPB), 0, stream,
                     x, bqkv, bproj, wt, (float*)d_out);
}